// Round 1
// baseline (293.146 us; speedup 1.0000x reference)
//
#include <hip/hip_runtime.h>
#include <hip/hip_bf16.h>
#include <stdint.h>

#define NUMH 16
#define HD   64
#define HID  1024
#define SEQ  2048
#define BATCH 2
#define NTOK (BATCH*SEQ)   // 4096
#define LN_EPS 1e-5f

typedef __attribute__((ext_vector_type(8))) short  short8;   // 8 bf16 (4 VGPRs)
typedef __attribute__((ext_vector_type(4))) float  f32x4;

#define AS1 __attribute__((address_space(1)))
#define AS3 __attribute__((address_space(3)))

__device__ __forceinline__ void gload_lds16(const void* g, void* l) {
  // LDS dest = wave-uniform base + lane*16 (HW); global addr is per-lane.
  __builtin_amdgcn_global_load_lds((const AS1 void*)g, (AS3 void*)l, 16, 0, 0);
}

__device__ __forceinline__ unsigned short f2bf(float f) {
  union { float f; unsigned u; } v; v.f = f;
  unsigned u = v.u;
  u += 0x7fffu + ((u >> 16) & 1u);   // RNE
  return (unsigned short)(u >> 16);
}

__device__ __forceinline__ f32x4 mfma16x16x32(short8 a, short8 b, f32x4 c) {
  return __builtin_amdgcn_mfma_f32_16x16x32_bf16(a, b, c, 0, 0, 0);
}

// ---------------- x fp32 -> bf16 ----------------
__global__ void k_conv_x(const float* __restrict__ x, unsigned short* __restrict__ xb) {
  int i = blockIdx.x * blockDim.x + threadIdx.x;   // one float4 per thread
  f32x4 v = ((const f32x4*)x)[i];
  unsigned short* o = xb + i * 4;
  o[0] = f2bf(v[0]); o[1] = f2bf(v[1]); o[2] = f2bf(v[2]); o[3] = f2bf(v[3]);
}

// ---------------- W [K][N] fp32 -> W^T [N][K] bf16 ----------------
__global__ void k_transw(const float* __restrict__ in, unsigned short* __restrict__ out) {
  __shared__ float t[32][33];
  int tx = threadIdx.x, ty = threadIdx.y;           // 32 x 8
  int x0 = blockIdx.x * 32, y0 = blockIdx.y * 32;
  for (int j = 0; j < 32; j += 8)
    t[ty + j][tx] = in[(y0 + ty + j) * HID + x0 + tx];
  __syncthreads();
  for (int j = 0; j < 32; j += 8)
    out[(x0 + ty + j) * HID + y0 + tx] = f2bf(t[tx][ty + j]);
}

// ---------------- GEMM: C[M][N] = A[M][K](bf16) * BT[N][K](bf16)^T ----------------
// 128x128 tile, BK=32, 4 waves (2x2), 16x16x32 MFMA. m97-style global_load_lds staging.
// MODE 0: QKV epilogue (N=3072): scatter to Q/K/V head layouts [BH][S][64], add bias.
// MODE 1: plain fp32 epilogue: out0[M][N] = acc + bias0[col].
template<int MODE>
__global__ __launch_bounds__(256, 2)
void k_gemm(const unsigned short* __restrict__ A, const unsigned short* __restrict__ BT,
            int M, int N, int K,
            const float* __restrict__ bias0, const float* __restrict__ bias1,
            const float* __restrict__ bias2,
            unsigned short* __restrict__ outQ, unsigned short* __restrict__ outK,
            unsigned short* __restrict__ outV, float* __restrict__ outF) {
  const int tid  = threadIdx.x;
  const int lane = tid & 63, wave = tid >> 6;
  const int l15 = lane & 15, lhi = lane >> 4;
  const int row0 = blockIdx.x * 128, col0 = blockIdx.y * 128;
  const int wrow = (wave >> 1) * 64, wcol = (wave & 1) * 64;

  __shared__ unsigned short As[128 * 32];
  __shared__ unsigned short Bs[128 * 32];

  f32x4 acc[4][4] = {};

  for (int kt = 0; kt < K; kt += 32) {
    // stage A (128x32 bf16 = 8KB) + B: per wave 2 chunks of 1KB each
    #pragma unroll
    for (int c = 0; c < 2; ++c) {
      int base = wave * 1024 + c * 4096;            // byte base (wave-uniform)
      int o = base + lane * 16;                     // this lane's byte offset
      int r = o >> 6, cb = o & 63;                  // row, col-byte (64B rows)
      gload_lds16(A  + (size_t)(row0 + r) * K + kt + (cb >> 1), As + (base >> 1));
      gload_lds16(BT + (size_t)(col0 + r) * K + kt + (cb >> 1), Bs + (base >> 1));
    }
    __syncthreads();

    short8 af[4], bf[4];
    #pragma unroll
    for (int m = 0; m < 4; ++m)
      af[m] = *(const short8*)(As + (wrow + m * 16 + l15) * 32 + lhi * 8);
    #pragma unroll
    for (int n = 0; n < 4; ++n)
      bf[n] = *(const short8*)(Bs + (wcol + n * 16 + l15) * 32 + lhi * 8);
    #pragma unroll
    for (int m = 0; m < 4; ++m)
      #pragma unroll
      for (int n = 0; n < 4; ++n)
        acc[m][n] = mfma16x16x32(af[m], bf[n], acc[m][n]);
    __syncthreads();
  }

  // epilogue: C row = (lane>>4)*4 + reg (+m*16), col = lane&15 (+n*16)  [m89 layout]
  #pragma unroll
  for (int m = 0; m < 4; ++m)
    #pragma unroll
    for (int n = 0; n < 4; ++n) {
      int col = col0 + wcol + n * 16 + l15;
      #pragma unroll
      for (int j = 0; j < 4; ++j) {
        int row = row0 + wrow + m * 16 + lhi * 4 + j;
        float v = acc[m][n][j];
        if (MODE == 0) {
          int proj = col >> 10, d = col & 1023;
          int h = d >> 6, hd = d & 63;
          int b = row >> 11, s = row & 2047;
          const float* bias = (proj == 0) ? bias0 : (proj == 1) ? bias1 : bias2;
          unsigned short* dst = (proj == 0) ? outQ : (proj == 1) ? outK : outV;
          dst[((size_t)((b * NUMH + h) * SEQ + s) << 6) + hd] = f2bf(v + bias[d]);
        } else {
          outF[(size_t)row * N + col] = v + bias0[col];
        }
      }
    }
}

// ---------------- V [BH][S][64] -> VT [BH][64][S] (bf16) ----------------
__global__ void k_vtrans(const unsigned short* __restrict__ V, unsigned short* __restrict__ VT) {
  __shared__ unsigned short t[64][65];
  int bh = blockIdx.y, s0 = blockIdx.x * 64;
  int tid = threadIdx.x;
  for (int it = 0; it < 16; ++it) {
    int idx = it * 256 + tid;
    int r = idx >> 6, c = idx & 63;
    t[r][c] = V[(size_t)(bh * SEQ + s0 + r) * 64 + c];
  }
  __syncthreads();
  for (int it = 0; it < 16; ++it) {
    int idx = it * 256 + tid;
    int d = idx >> 6, sl = idx & 63;
    VT[(size_t)(bh * 64 + d) * SEQ + s0 + sl] = t[sl][d];
  }
}

// ---------------- flash attention ----------------
// grid (S/64, B*H), 256 thr. Each wave owns a 16-row Q strip; KBLK=64.
// K tile [64 key][64 d], VT tile [64 d][64 key] staged via global_load_lds with
// pre-swizzled SOURCE (rule #21); reads XOR the same ((row&7)<<4). P round-trips
// through per-wave swizzled LDS to become the PV A-operand.
__global__ __launch_bounds__(256, 2)
void k_attn(const unsigned short* __restrict__ Q, const unsigned short* __restrict__ Kk,
            const unsigned short* __restrict__ VT, const float* __restrict__ mask,
            unsigned short* __restrict__ ctx) {
  const int tid = threadIdx.x, lane = tid & 63, wave = tid >> 6;
  const int l15 = lane & 15, lhi = lane >> 4;
  const int bh = blockIdx.y, b = bh >> 4, h = bh & 15;
  const int qs = blockIdx.x * 64 + wave * 16;     // this wave's Q strip base (in [0,SEQ))

  __shared__ unsigned short Ks[64 * 64];
  __shared__ unsigned short Vs[64 * 64];
  __shared__ unsigned short Ps[4][16 * 64];

  short8 qf[2];
  #pragma unroll
  for (int t = 0; t < 2; ++t)
    qf[t] = *(const short8*)(Q + ((size_t)bh * SEQ + qs + l15) * 64 + t * 32 + lhi * 8);

  float mr[4], lr[4];
  f32x4 cacc[4] = {};
  #pragma unroll
  for (int j = 0; j < 4; ++j) { mr[j] = -1e30f; lr[j] = 0.f; }

  const float scale = 0.125f;
  const float LOG2E = 1.44269504088896340736f;
  unsigned short* Pw = Ps[wave];

  for (int kt = 0; kt < SEQ; kt += 64) {
    #pragma unroll
    for (int c = 0; c < 2; ++c) {
      int base = wave * 1024 + c * 4096;
      int o = base + lane * 16;
      int r = o >> 7, cb = o & 127;
      int scb = cb ^ ((r & 7) << 4);               // pre-swizzle the SOURCE
      gload_lds16(Kk + ((size_t)bh * SEQ + kt + r) * 64 + (scb >> 1), Ks + (base >> 1));
      gload_lds16(VT + ((size_t)bh * 64 + r) * SEQ + kt + (scb >> 1), Vs + (base >> 1));
    }
    __syncthreads();

    // S = Q K^T  (rows=q, cols=key)
    f32x4 sf[4] = {};
    #pragma unroll
    for (int t = 0; t < 2; ++t)
      #pragma unroll
      for (int n = 0; n < 4; ++n) {
        int row = n * 16 + l15;
        int cb = (t * 64 + lhi * 16) ^ ((row & 7) << 4);
        short8 kf = *(const short8*)((const char*)Ks + row * 128 + cb);
        sf[n] = mfma16x16x32(qf[t], kf, sf[n]);
      }

    float mk[4];
    #pragma unroll
    for (int n = 0; n < 4; ++n) mk[n] = mask[b * SEQ + kt + n * 16 + l15];

    float pj[4][4];
    #pragma unroll
    for (int n = 0; n < 4; ++n)
      #pragma unroll
      for (int j = 0; j < 4; ++j) pj[n][j] = sf[n][j] * scale + mk[n];

    #pragma unroll
    for (int j = 0; j < 4; ++j) {
      float tm = fmaxf(fmaxf(pj[0][j], pj[1][j]), fmaxf(pj[2][j], pj[3][j]));
      #pragma unroll
      for (int off = 1; off < 16; off <<= 1) tm = fmaxf(tm, __shfl_xor(tm, off));
      float mnew = fmaxf(mr[j], tm);
      float alpha = exp2f((mr[j] - mnew) * LOG2E);
      float rs = 0.f;
      #pragma unroll
      for (int n = 0; n < 4; ++n) {
        float p = exp2f((pj[n][j] - mnew) * LOG2E);
        pj[n][j] = p; rs += p;
      }
      #pragma unroll
      for (int off = 1; off < 16; off <<= 1) rs += __shfl_xor(rs, off);
      lr[j] = lr[j] * alpha + rs;
      mr[j] = mnew;
      #pragma unroll
      for (int n = 0; n < 4; ++n) cacc[n][j] *= alpha;
    }

    // P -> per-wave LDS (bf16, swizzled); same-wave LDS ops are ordered, no barrier
    #pragma unroll
    for (int n = 0; n < 4; ++n)
      #pragma unroll
      for (int j = 0; j < 4; ++j) {
        int row = lhi * 4 + j, col = n * 16 + l15;
        int byte = (row * 128 + col * 2) ^ ((row & 7) << 4);
        *(unsigned short*)((char*)Pw + byte) = f2bf(pj[n][j]);
      }

    // O += P V   (A = P [16 q][64 key], B = VT [d][key])
    #pragma unroll
    for (int t = 0; t < 2; ++t) {
      int pb = (l15 * 128 + t * 64 + lhi * 16) ^ ((l15 & 7) << 4);
      short8 pf = *(const short8*)((const char*)Pw + pb);
      #pragma unroll
      for (int n = 0; n < 4; ++n) {
        int vrow = n * 16 + l15;
        int vb = vrow * 128 + ((t * 64 + lhi * 16) ^ ((vrow & 7) << 4));
        short8 vf = *(const short8*)((const char*)Vs + vb);
        cacc[n] = mfma16x16x32(pf, vf, cacc[n]);
      }
    }
    __syncthreads();
  }

  #pragma unroll
  for (int j = 0; j < 4; ++j) {
    float inv = 1.f / lr[j];
    int q = qs + lhi * 4 + j;
    #pragma unroll
    for (int n = 0; n < 4; ++n) {
      int d = n * 16 + l15;
      ctx[(size_t)(b * SEQ + q) * HID + h * 64 + d] = f2bf(cacc[n][j] * inv);
    }
  }
}

// ---------------- residual + LayerNorm ----------------
__global__ __launch_bounds__(256)
void k_ln(const float* __restrict__ ao, const float* __restrict__ x,
          const float* __restrict__ gamma, const float* __restrict__ beta,
          float* __restrict__ out) {
  int row = blockIdx.x, tid = threadIdx.x;
  f32x4 v = ((const f32x4*)(ao + (size_t)row * HID))[tid]
          + ((const f32x4*)(x  + (size_t)row * HID))[tid];
  float s = v[0] + v[1] + v[2] + v[3];
  float ss = v[0]*v[0] + v[1]*v[1] + v[2]*v[2] + v[3]*v[3];
  #pragma unroll
  for (int off = 1; off < 64; off <<= 1) { s += __shfl_xor(s, off); ss += __shfl_xor(ss, off); }
  __shared__ float sb[4], ssb[4];
  int wave = tid >> 6, lane = tid & 63;
  if (lane == 0) { sb[wave] = s; ssb[wave] = ss; }
  __syncthreads();
  float ts = sb[0] + sb[1] + sb[2] + sb[3];
  float tss = ssb[0] + ssb[1] + ssb[2] + ssb[3];
  float mu = ts * (1.f / HID);
  float var = tss * (1.f / HID) - mu * mu;
  float rstd = rsqrtf(var + LN_EPS);
  f32x4 g = ((const f32x4*)gamma)[tid];
  f32x4 be = ((const f32x4*)beta)[tid];
  f32x4 o;
  #pragma unroll
  for (int i = 0; i < 4; ++i) o[i] = (v[i] - mu) * rstd * g[i] + be[i];
  ((f32x4*)(out + (size_t)row * HID))[tid] = o;
}

extern "C" void kernel_launch(void* const* d_in, const int* in_sizes, int n_in,
                              void* d_out, int out_size, void* d_ws, size_t ws_size,
                              hipStream_t stream) {
  const float* x     = (const float*)d_in[0];
  const float* mask  = (const float*)d_in[1];
  const float* Wq    = (const float*)d_in[2];
  const float* bq    = (const float*)d_in[3];
  const float* Wk    = (const float*)d_in[4];
  const float* bk    = (const float*)d_in[5];
  const float* Wv    = (const float*)d_in[6];
  const float* bv    = (const float*)d_in[7];
  const float* Wo    = (const float*)d_in[8];
  const float* bo    = (const float*)d_in[9];
  const float* gamma = (const float*)d_in[10];
  const float* beta  = (const float*)d_in[11];
  float* out = (float*)d_out;

  char* w = (char*)d_ws;
  unsigned short* xb    = (unsigned short*)w; w += (size_t)NTOK * HID * 2;   // 8 MB
  unsigned short* WqkvT = (unsigned short*)w; w += (size_t)3 * HID * HID * 2;// 6 MB
  unsigned short* WoT   = (unsigned short*)w; w += (size_t)HID * HID * 2;    // 2 MB
  unsigned short* Qh    = (unsigned short*)w; w += (size_t)NTOK * HID * 2;   // 8 MB
  unsigned short* Kh    = (unsigned short*)w; w += (size_t)NTOK * HID * 2;   // 8 MB
  unsigned short* Vh    = (unsigned short*)w; w += (size_t)NTOK * HID * 2;   // 8 MB
  unsigned short* VTh   = (unsigned short*)w; w += (size_t)NTOK * HID * 2;   // 8 MB
  unsigned short* ctxb  = (unsigned short*)w; w += (size_t)NTOK * HID * 2;   // 8 MB
  float*          attn  = (float*)w;          w += (size_t)NTOK * HID * 4;   // 16 MB
  (void)ws_size; (void)in_sizes; (void)n_in; (void)out_size;

  k_conv_x<<<NTOK * HID / 4 / 256, 256, 0, stream>>>(x, xb);
  dim3 tb(32, 8);
  k_transw<<<dim3(32, 32), tb, 0, stream>>>(Wq, WqkvT);
  k_transw<<<dim3(32, 32), tb, 0, stream>>>(Wk, WqkvT + (size_t)HID * HID);
  k_transw<<<dim3(32, 32), tb, 0, stream>>>(Wv, WqkvT + (size_t)2 * HID * HID);
  k_transw<<<dim3(32, 32), tb, 0, stream>>>(Wo, WoT);

  k_gemm<0><<<dim3(NTOK / 128, 3 * HID / 128), 256, 0, stream>>>(
      xb, WqkvT, NTOK, 3 * HID, HID, bq, bk, bv, Qh, Kh, Vh, nullptr);

  k_vtrans<<<dim3(SEQ / 64, BATCH * NUMH), 256, 0, stream>>>(Vh, VTh);

  k_attn<<<dim3(SEQ / 64, BATCH * NUMH), 256, 0, stream>>>(Qh, Kh, VTh, mask, ctxb);

  k_gemm<1><<<dim3(NTOK / 128, HID / 128), 256, 0, stream>>>(
      ctxb, WoT, NTOK, HID, HID, bo, nullptr, nullptr, nullptr, nullptr, nullptr, attn);

  k_ln<<<NTOK, 256, 0, stream>>>(attn, x, gamma, beta, out);
}

// Round 2
// 248.166 us; speedup vs baseline: 1.1812x; 1.1812x over previous
//
#include <hip/hip_runtime.h>
#include <hip/hip_bf16.h>
#include <stdint.h>

#define NUMH 16
#define HD   64
#define HID  1024
#define SEQ  2048
#define BATCH 2
#define NTOK (BATCH*SEQ)   // 4096
#define LN_EPS 1e-5f

typedef __attribute__((ext_vector_type(8)))  short  short8;   // 8 bf16 (4 VGPRs)
typedef __attribute__((ext_vector_type(4)))  float  f32x4;
typedef __attribute__((ext_vector_type(16))) float  f32x16;

#define AS1 __attribute__((address_space(1)))
#define AS3 __attribute__((address_space(3)))

__device__ __forceinline__ void gload_lds16(const void* g, void* l) {
  // LDS dest = wave-uniform base + lane*16 (HW); global addr is per-lane.
  __builtin_amdgcn_global_load_lds((const AS1 void*)g, (AS3 void*)l, 16, 0, 0);
}

__device__ __forceinline__ unsigned short f2bf(float f) {
  union { float f; unsigned u; } v; v.f = f;
  unsigned u = v.u;
  u += 0x7fffu + ((u >> 16) & 1u);   // RNE
  return (unsigned short)(u >> 16);
}

__device__ __forceinline__ f32x4 mfma16x16x32(short8 a, short8 b, f32x4 c) {
  return __builtin_amdgcn_mfma_f32_16x16x32_bf16(a, b, c, 0, 0, 0);
}
__device__ __forceinline__ f32x16 mfma32x32x16(short8 a, short8 b, f32x16 c) {
  return __builtin_amdgcn_mfma_f32_32x32x16_bf16(a, b, c, 0, 0, 0);
}

// pack two f32 -> dword of 2 bf16 (lo = first arg), HW RNE
__device__ __forceinline__ unsigned cvtpk(float lo, float hi) {
  unsigned r;
  asm("v_cvt_pk_bf16_f32 %0, %1, %2" : "=v"(r) : "v"(lo), "v"(hi));
  return r;
}
// swap upper 32 lanes of a with lower 32 lanes of b (both modified)
__device__ __forceinline__ void perm32swap(unsigned &a, unsigned &b) {
  asm volatile("v_permlane32_swap_b32 %0, %1" : "+v"(a), "+v"(b));
}

// ---------------- x fp32 -> bf16 ----------------
__global__ void k_conv_x(const float* __restrict__ x, unsigned short* __restrict__ xb) {
  int i = blockIdx.x * blockDim.x + threadIdx.x;   // one float4 per thread
  f32x4 v = ((const f32x4*)x)[i];
  unsigned short* o = xb + i * 4;
  o[0] = f2bf(v[0]); o[1] = f2bf(v[1]); o[2] = f2bf(v[2]); o[3] = f2bf(v[3]);
}

// ---------------- W [K][N] fp32 -> W^T [N][K] bf16 ----------------
__global__ void k_transw(const float* __restrict__ in, unsigned short* __restrict__ out) {
  __shared__ float t[32][33];
  int tx = threadIdx.x, ty = threadIdx.y;           // 32 x 8
  int x0 = blockIdx.x * 32, y0 = blockIdx.y * 32;
  for (int j = 0; j < 32; j += 8)
    t[ty + j][tx] = in[(y0 + ty + j) * HID + x0 + tx];
  __syncthreads();
  for (int j = 0; j < 32; j += 8)
    out[(x0 + ty + j) * HID + y0 + tx] = f2bf(t[tx][ty + j]);
}

// ---------------- GEMM: C[M][N] = A[M][K](bf16) * BT[N][K](bf16)^T ----------------
template<int MODE>
__global__ __launch_bounds__(256, 2)
void k_gemm(const unsigned short* __restrict__ A, const unsigned short* __restrict__ BT,
            int M, int N, int K,
            const float* __restrict__ bias0, const float* __restrict__ bias1,
            const float* __restrict__ bias2,
            unsigned short* __restrict__ outQ, unsigned short* __restrict__ outK,
            unsigned short* __restrict__ outV, float* __restrict__ outF) {
  const int tid  = threadIdx.x;
  const int lane = tid & 63, wave = tid >> 6;
  const int l15 = lane & 15, lhi = lane >> 4;
  const int row0 = blockIdx.x * 128, col0 = blockIdx.y * 128;
  const int wrow = (wave >> 1) * 64, wcol = (wave & 1) * 64;

  __shared__ unsigned short As[128 * 32];
  __shared__ unsigned short Bs[128 * 32];

  f32x4 acc[4][4] = {};

  for (int kt = 0; kt < K; kt += 32) {
    #pragma unroll
    for (int c = 0; c < 2; ++c) {
      int base = wave * 1024 + c * 4096;            // byte base (wave-uniform)
      int o = base + lane * 16;                     // this lane's byte offset
      int r = o >> 6, cb = o & 63;                  // row, col-byte (64B rows)
      gload_lds16(A  + (size_t)(row0 + r) * K + kt + (cb >> 1), As + (base >> 1));
      gload_lds16(BT + (size_t)(col0 + r) * K + kt + (cb >> 1), Bs + (base >> 1));
    }
    __syncthreads();

    short8 af[4], bf[4];
    #pragma unroll
    for (int m = 0; m < 4; ++m)
      af[m] = *(const short8*)(As + (wrow + m * 16 + l15) * 32 + lhi * 8);
    #pragma unroll
    for (int n = 0; n < 4; ++n)
      bf[n] = *(const short8*)(Bs + (wcol + n * 16 + l15) * 32 + lhi * 8);
    #pragma unroll
    for (int m = 0; m < 4; ++m)
      #pragma unroll
      for (int n = 0; n < 4; ++n)
        acc[m][n] = mfma16x16x32(af[m], bf[n], acc[m][n]);
    __syncthreads();
  }

  #pragma unroll
  for (int m = 0; m < 4; ++m)
    #pragma unroll
    for (int n = 0; n < 4; ++n) {
      int col = col0 + wcol + n * 16 + l15;
      #pragma unroll
      for (int j = 0; j < 4; ++j) {
        int row = row0 + wrow + m * 16 + lhi * 4 + j;
        float v = acc[m][n][j];
        if (MODE == 0) {
          int proj = col >> 10, d = col & 1023;
          int h = d >> 6, hd = d & 63;
          int b = row >> 11, s = row & 2047;
          const float* bias = (proj == 0) ? bias0 : (proj == 1) ? bias1 : bias2;
          unsigned short* dst = (proj == 0) ? outQ : (proj == 1) ? outK : outV;
          dst[((size_t)((b * NUMH + h) * SEQ + s) << 6) + hd] = f2bf(v + bias[d]);
        } else {
          outF[(size_t)row * N + col] = v + bias0[col];
        }
      }
    }
}

// ---------------- V [BH][S][64] -> VT [BH][64][S] (bf16) ----------------
__global__ void k_vtrans(const unsigned short* __restrict__ V, unsigned short* __restrict__ VT) {
  __shared__ unsigned short t[64][65];
  int bh = blockIdx.y, s0 = blockIdx.x * 64;
  int tid = threadIdx.x;
  for (int it = 0; it < 16; ++it) {
    int idx = it * 256 + tid;
    int r = idx >> 6, c = idx & 63;
    t[r][c] = V[(size_t)(bh * SEQ + s0 + r) * 64 + c];
  }
  __syncthreads();
  for (int it = 0; it < 16; ++it) {
    int idx = it * 256 + tid;
    int d = idx >> 6, sl = idx & 63;
    VT[(size_t)(bh * 64 + d) * SEQ + s0 + sl] = t[sl][d];
  }
}

// ---------------- flash attention: swapped-QK^T 32x32 structure (m214 port) ----
// grid (SEQ/128, B*H), 256 thr. Each wave owns 32 q-rows; KVBLK=64.
// S = mfma32(A=K_frag, B=Q_frag): C[row=key', col=q'] with
//   row(reg r) = (r&3) + 8*(r>>2) + 4*hi,  col = lane&31   [m74/m101 layout]
// => lane (hi,l31) holds P[q=l31][32 keys of its hi-half] fully in registers.
// Softmax reduce = 31 in-reg ops + 1 shfl_xor(32). P -> PV A-frag via
// cvt_pk_bf16 + permlane32_swap (T12): for slot ks (16 keys), every lane needs
// own p[8(ks&1)+0..3] and partner's p[8(ks&1)+0..3] (hi=0), or the +4..7 group
// (hi=1); {w0,w2}=swap(cvtpk(p0,p1),cvtpk(p4,p5)), {w1,w3}=swap(cvtpk(p2,p3),
// cvtpk(p6,p7)) fills the 4 frag dwords exactly.
__global__ __launch_bounds__(256, 2)
void k_attn(const unsigned short* __restrict__ Q, const unsigned short* __restrict__ Kk,
            const unsigned short* __restrict__ VT, const float* __restrict__ mask,
            unsigned short* __restrict__ ctx) {
  const int tid = threadIdx.x, lane = tid & 63, wave = tid >> 6;
  const int l31 = lane & 31, hi = lane >> 5;
  const int bh = blockIdx.y, b = bh >> 4, h = bh & 15;
  const int qs = blockIdx.x * 128 + wave * 32;    // this wave's 32 q-rows

  __shared__ __align__(16) unsigned short Ks[64 * 64];   // [64 key][64 d], XOR-swizzled
  __shared__ __align__(16) unsigned short Vs[64 * 64];   // [64 d][64 key], XOR-swizzled
  __shared__ __align__(16) float sLds[4][32];            // per-wave alpha / l broadcast

  // Q frag (B-operand): lane holds Q[qs+l31][ks*16 + hi*8 + i], i=0..7
  short8 qf[4];
  {
    const unsigned short* qrow = Q + ((size_t)bh * SEQ + qs + l31) * 64 + hi * 8;
    #pragma unroll
    for (int ks = 0; ks < 4; ++ks) qf[ks] = *(const short8*)(qrow + ks * 16);
  }

  f32x16 o0 = {}, o1 = {};          // O[q=crow(r,hi)][d = l31 | 32+l31]
  float mr = -3.0e38f, lr = 0.f;
  const float LOG2E = 1.44269504088896340736f;
  const float scale = 0.125f;       // 1/sqrt(64)
  const int sw = (l31 & 7) << 4;    // read-side XOR swizzle (row&7 == l31&7 for both 32-halves)

  for (int kt = 0; kt < SEQ; kt += 64) {
    // ---- stage K tile + VT tile (linear LDS dest, pre-swizzled global src) ----
    #pragma unroll
    for (int c = 0; c < 2; ++c) {
      int base = wave * 1024 + c * 4096;
      int off = base + lane * 16;
      int r = off >> 7, cb = off & 127;
      int scb = cb ^ ((r & 7) << 4);
      gload_lds16(Kk + ((size_t)bh * SEQ + kt + r) * 64 + (scb >> 1), Ks + (base >> 1));
      gload_lds16(VT + ((size_t)bh * 64 + r) * SEQ + kt + (scb >> 1), Vs + (base >> 1));
    }
    __syncthreads();

    // ---- S = K Q^T (swapped): s0 = keys kt+0..31, s1 = keys kt+32..63 ----
    f32x16 s0 = {}, s1 = {};
    #pragma unroll
    for (int ks = 0; ks < 4; ++ks) {
      int cb = ((ks * 16 + hi * 8) * 2) ^ sw;
      short8 k0 = *(const short8*)((const char*)Ks + l31 * 128 + cb);
      short8 k1 = *(const short8*)((const char*)Ks + (32 + l31) * 128 + cb);
      s0 = mfma32x32x16(k0, qf[ks], s0);
      s1 = mfma32x32x16(k1, qf[ks], s1);
    }

    // ---- mask (tiny, L2-hot): key(r) = 32*kb + 8*(r>>2) + 4*hi + (r&3) ----
    f32x4 mk0[4], mk1[4];
    #pragma unroll
    for (int rq = 0; rq < 4; ++rq) {
      mk0[rq] = *(const f32x4*)(mask + b * SEQ + kt + rq * 8 + hi * 4);
      mk1[rq] = *(const f32x4*)(mask + b * SEQ + kt + 32 + rq * 8 + hi * 4);
    }
    #pragma unroll
    for (int r = 0; r < 16; ++r) {
      s0[r] = fmaf(s0[r], scale, mk0[r >> 2][r & 3]);
      s1[r] = fmaf(s1[r], scale, mk1[r >> 2][r & 3]);
    }

    // ---- online softmax (per q = l31; partner lane hi^1 has other 32 keys) ----
    float tmax = fmaxf(s0[0], s1[0]);
    #pragma unroll
    for (int r = 1; r < 16; ++r) tmax = fmaxf(tmax, fmaxf(s0[r], s1[r]));
    tmax = fmaxf(tmax, __shfl_xor(tmax, 32));

    if (!__all(tmax <= mr + 8.0f)) {          // defer-max (T13, THR=8)
      float mnew = fmaxf(mr, tmax);
      float alpha = exp2f((mr - mnew) * LOG2E);
      mr = mnew; lr *= alpha;
      if (hi == 0) sLds[wave][l31] = alpha;   // redistribute alpha: col-index -> row-index
      f32x4 av[4];
      #pragma unroll
      for (int rq = 0; rq < 4; ++rq) av[rq] = *(const f32x4*)&sLds[wave][rq * 8 + hi * 4];
      #pragma unroll
      for (int r = 0; r < 16; ++r) {
        o0[r] *= av[r >> 2][r & 3];
        o1[r] *= av[r >> 2][r & 3];
      }
    }

    float mL = mr * LOG2E;
    float rs = 0.f;
    #pragma unroll
    for (int r = 0; r < 16; ++r) {
      float p0 = exp2f(fmaf(s0[r], LOG2E, -mL));
      float p1 = exp2f(fmaf(s1[r], LOG2E, -mL));
      s0[r] = p0; s1[r] = p1; rs += p0 + p1;
    }
    rs += __shfl_xor(rs, 32);
    lr += rs;

    // ---- P -> bf16 A-frags via cvt_pk + permlane32_swap (T12) ----
    unsigned pw[4][4];
    #pragma unroll
    for (int ks = 0; ks < 4; ++ks) {
      int ro = 8 * (ks & 1);
      unsigned a0, a1, b0, b1;
      if (ks < 2) {
        a0 = cvtpk(s0[ro + 0], s0[ro + 1]); a1 = cvtpk(s0[ro + 2], s0[ro + 3]);
        b0 = cvtpk(s0[ro + 4], s0[ro + 5]); b1 = cvtpk(s0[ro + 6], s0[ro + 7]);
      } else {
        a0 = cvtpk(s1[ro + 0], s1[ro + 1]); a1 = cvtpk(s1[ro + 2], s1[ro + 3]);
        b0 = cvtpk(s1[ro + 4], s1[ro + 5]); b1 = cvtpk(s1[ro + 6], s1[ro + 7]);
      }
      perm32swap(a0, b0);
      perm32swap(a1, b1);
      pw[ks][0] = a0; pw[ks][1] = a1; pw[ks][2] = b0; pw[ks][3] = b1;
    }

    // ---- O += P V ----
    #pragma unroll
    for (int ks = 0; ks < 4; ++ks) {
      union { unsigned u[4]; short8 s; } pu;
      pu.u[0] = pw[ks][0]; pu.u[1] = pw[ks][1]; pu.u[2] = pw[ks][2]; pu.u[3] = pw[ks][3];
      int cb = ((ks * 16 + hi * 8) * 2) ^ sw;
      short8 v0 = *(const short8*)((const char*)Vs + l31 * 128 + cb);
      short8 v1 = *(const short8*)((const char*)Vs + (32 + l31) * 128 + cb);
      o0 = mfma32x32x16(pu.s, v0, o0);
      o1 = mfma32x32x16(pu.s, v1, o1);
    }
    __syncthreads();
  }

  // ---- epilogue: redistribute l (col-index -> row-index), normalize, store ----
  if (hi == 0) sLds[wave][l31] = lr;
  f32x4 lv[4];
  #pragma unroll
  for (int rq = 0; rq < 4; ++rq) {
    f32x4 t = *(const f32x4*)&sLds[wave][rq * 8 + hi * 4];
    lv[rq][0] = 1.f / t[0]; lv[rq][1] = 1.f / t[1];
    lv[rq][2] = 1.f / t[2]; lv[rq][3] = 1.f / t[3];
  }
  #pragma unroll
  for (int r = 0; r < 16; ++r) {
    int q = qs + (r & 3) + 8 * (r >> 2) + 4 * hi;
    float inv = lv[r >> 2][r & 3];
    unsigned short* dst = ctx + (size_t)(b * SEQ + q) * HID + h * 64;
    dst[l31]      = f2bf(o0[r] * inv);
    dst[32 + l31] = f2bf(o1[r] * inv);
  }
}

// ---------------- residual + LayerNorm ----------------
__global__ __launch_bounds__(256)
void k_ln(const float* __restrict__ ao, const float* __restrict__ x,
          const float* __restrict__ gamma, const float* __restrict__ beta,
          float* __restrict__ out) {
  int row = blockIdx.x, tid = threadIdx.x;
  f32x4 v = ((const f32x4*)(ao + (size_t)row * HID))[tid]
          + ((const f32x4*)(x  + (size_t)row * HID))[tid];
  float s = v[0] + v[1] + v[2] + v[3];
  float ss = v[0]*v[0] + v[1]*v[1] + v[2]*v[2] + v[3]*v[3];
  #pragma unroll
  for (int off = 1; off < 64; off <<= 1) { s += __shfl_xor(s, off); ss += __shfl_xor(ss, off); }
  __shared__ float sb[4], ssb[4];
  int wave = tid >> 6, lane = tid & 63;
  if (lane == 0) { sb[wave] = s; ssb[wave] = ss; }
  __syncthreads();
  float ts = sb[0] + sb[1] + sb[2] + sb[3];
  float tss = ssb[0] + ssb[1] + ssb[2] + ssb[3];
  float mu = ts * (1.f / HID);
  float var = tss * (1.f / HID) - mu * mu;
  float rstd = rsqrtf(var + LN_EPS);
  f32x4 g = ((const f32x4*)gamma)[tid];
  f32x4 be = ((const f32x4*)beta)[tid];
  f32x4 o;
  #pragma unroll
  for (int i = 0; i < 4; ++i) o[i] = (v[i] - mu) * rstd * g[i] + be[i];
  ((f32x4*)(out + (size_t)row * HID))[tid] = o;
}

extern "C" void kernel_launch(void* const* d_in, const int* in_sizes, int n_in,
                              void* d_out, int out_size, void* d_ws, size_t ws_size,
                              hipStream_t stream) {
  const float* x     = (const float*)d_in[0];
  const float* mask  = (const float*)d_in[1];
  const float* Wq    = (const float*)d_in[2];
  const float* bq    = (const float*)d_in[3];
  const float* Wk    = (const float*)d_in[4];
  const float* bk    = (const float*)d_in[5];
  const float* Wv    = (const float*)d_in[6];
  const float* bv    = (const float*)d_in[7];
  const float* Wo    = (const float*)d_in[8];
  const float* bo    = (const float*)d_in[9];
  const float* gamma = (const float*)d_in[10];
  const float* beta  = (const float*)d_in[11];
  float* out = (float*)d_out;

  char* w = (char*)d_ws;
  unsigned short* xb    = (unsigned short*)w; w += (size_t)NTOK * HID * 2;   // 8 MB
  unsigned short* WqkvT = (unsigned short*)w; w += (size_t)3 * HID * HID * 2;// 6 MB
  unsigned short* WoT   = (unsigned short*)w; w += (size_t)HID * HID * 2;    // 2 MB
  unsigned short* Qh    = (unsigned short*)w; w += (size_t)NTOK * HID * 2;   // 8 MB
  unsigned short* Kh    = (unsigned short*)w; w += (size_t)NTOK * HID * 2;   // 8 MB
  unsigned short* Vh    = (unsigned short*)w; w += (size_t)NTOK * HID * 2;   // 8 MB
  unsigned short* VTh   = (unsigned short*)w; w += (size_t)NTOK * HID * 2;   // 8 MB
  unsigned short* ctxb  = (unsigned short*)w; w += (size_t)NTOK * HID * 2;   // 8 MB
  float*          attn  = (float*)w;          w += (size_t)NTOK * HID * 4;   // 16 MB
  (void)ws_size; (void)in_sizes; (void)n_in; (void)out_size;

  k_conv_x<<<NTOK * HID / 4 / 256, 256, 0, stream>>>(x, xb);
  dim3 tb(32, 8);
  k_transw<<<dim3(32, 32), tb, 0, stream>>>(Wq, WqkvT);
  k_transw<<<dim3(32, 32), tb, 0, stream>>>(Wk, WqkvT + (size_t)HID * HID);
  k_transw<<<dim3(32, 32), tb, 0, stream>>>(Wv, WqkvT + (size_t)2 * HID * HID);
  k_transw<<<dim3(32, 32), tb, 0, stream>>>(Wo, WoT);

  k_gemm<0><<<dim3(NTOK / 128, 3 * HID / 128), 256, 0, stream>>>(
      xb, WqkvT, NTOK, 3 * HID, HID, bq, bk, bv, Qh, Kh, Vh, nullptr);

  k_vtrans<<<dim3(SEQ / 64, BATCH * NUMH), 256, 0, stream>>>(Vh, VTh);

  k_attn<<<dim3(SEQ / 128, BATCH * NUMH), 256, 0, stream>>>(Qh, Kh, VTh, mask, ctxb);

  k_gemm<1><<<dim3(NTOK / 128, HID / 128), 256, 0, stream>>>(
      ctxb, WoT, NTOK, HID, HID, bo, nullptr, nullptr, nullptr, nullptr, nullptr, attn);

  k_ln<<<NTOK, 256, 0, stream>>>(attn, x, gamma, beta, out);
}

// Round 3
// 233.764 us; speedup vs baseline: 1.2540x; 1.0616x over previous
//
#include <hip/hip_runtime.h>
#include <hip/hip_bf16.h>
#include <stdint.h>

#define NUMH 16
#define HD   64
#define HID  1024
#define SEQ  2048
#define BATCH 2
#define NTOK (BATCH*SEQ)   // 4096
#define LN_EPS 1e-5f

typedef __attribute__((ext_vector_type(8)))  short  short8;   // 8 bf16 (4 VGPRs)
typedef __attribute__((ext_vector_type(4)))  float  f32x4;
typedef __attribute__((ext_vector_type(16))) float  f32x16;

#define AS1 __attribute__((address_space(1)))
#define AS3 __attribute__((address_space(3)))

__device__ __forceinline__ void gload_lds16(const void* g, void* l) {
  // LDS dest = wave-uniform base + lane*16 (HW); global addr is per-lane.
  __builtin_amdgcn_global_load_lds((const AS1 void*)g, (AS3 void*)l, 16, 0, 0);
}

__device__ __forceinline__ unsigned short f2bf(float f) {
  union { float f; unsigned u; } v; v.f = f;
  unsigned u = v.u;
  u += 0x7fffu + ((u >> 16) & 1u);   // RNE
  return (unsigned short)(u >> 16);
}

__device__ __forceinline__ f32x4 mfma16x16x32(short8 a, short8 b, f32x4 c) {
  return __builtin_amdgcn_mfma_f32_16x16x32_bf16(a, b, c, 0, 0, 0);
}
__device__ __forceinline__ f32x16 mfma32x32x16(short8 a, short8 b, f32x16 c) {
  return __builtin_amdgcn_mfma_f32_32x32x16_bf16(a, b, c, 0, 0, 0);
}

// pack two f32 -> dword of 2 bf16 (lo = first arg), HW RNE
__device__ __forceinline__ unsigned cvtpk(float lo, float hi) {
  unsigned r;
  asm("v_cvt_pk_bf16_f32 %0, %1, %2" : "=v"(r) : "v"(lo), "v"(hi));
  return r;
}
// swap upper 32 lanes of a with lower 32 lanes of b (both modified)
__device__ __forceinline__ void perm32swap(unsigned &a, unsigned &b) {
  asm volatile("v_permlane32_swap_b32 %0, %1" : "+v"(a), "+v"(b));
}
// cross-half (lane i <-> lane i^32) reduce helpers via permlane32_swap
__device__ __forceinline__ float xhalf_max(float x) {
  union { float f; unsigned u; } a, b; a.f = x; b.f = x;
  perm32swap(a.u, b.u);
  return fmaxf(a.f, b.f);
}
__device__ __forceinline__ float xhalf_sum(float x) {
  union { float f; unsigned u; } a, b; a.f = x; b.f = x;
  perm32swap(a.u, b.u);
  return a.f + b.f;
}

// ---------------- x fp32 -> bf16 ----------------
__global__ void k_conv_x(const float* __restrict__ x, unsigned short* __restrict__ xb) {
  int i = blockIdx.x * blockDim.x + threadIdx.x;   // one float4 per thread
  f32x4 v = ((const f32x4*)x)[i];
  unsigned short* o = xb + i * 4;
  o[0] = f2bf(v[0]); o[1] = f2bf(v[1]); o[2] = f2bf(v[2]); o[3] = f2bf(v[3]);
}

// ---------------- all 4 weights: W [K][N] fp32 -> W^T [N][K] bf16 (one launch) ----
__global__ void k_transw_all(const float* __restrict__ Wq, const float* __restrict__ Wk,
                             const float* __restrict__ Wv, const float* __restrict__ Wo,
                             unsigned short* __restrict__ WqkvT, unsigned short* __restrict__ WoT) {
  __shared__ float t[32][33];
  int z = blockIdx.z;
  const float* in = (z == 0) ? Wq : (z == 1) ? Wk : (z == 2) ? Wv : Wo;
  unsigned short* out = (z < 3) ? WqkvT + (size_t)z * HID * HID : WoT;
  int tx = threadIdx.x, ty = threadIdx.y;           // 32 x 8
  int x0 = blockIdx.x * 32, y0 = blockIdx.y * 32;
  for (int j = 0; j < 32; j += 8)
    t[ty + j][tx] = in[(y0 + ty + j) * HID + x0 + tx];
  __syncthreads();
  for (int j = 0; j < 32; j += 8)
    out[(x0 + ty + j) * HID + y0 + tx] = f2bf(t[tx][ty + j]);
}

// ---------------- GEMM: C[M][N] = A[M][K](bf16) * BT[N][K](bf16)^T ----------------
// MODE 0: QKV epilogue: scatter to Q/K/V head layouts [BH][S][64], add bias.
// MODE 1: fp32 epilogue with fused residual: outF = acc + bias0[col] + resid[row][col].
template<int MODE>
__global__ __launch_bounds__(256, 2)
void k_gemm(const unsigned short* __restrict__ A, const unsigned short* __restrict__ BT,
            int M, int N, int K,
            const float* __restrict__ bias0, const float* __restrict__ bias1,
            const float* __restrict__ bias2, const float* __restrict__ resid,
            unsigned short* __restrict__ outQ, unsigned short* __restrict__ outK,
            unsigned short* __restrict__ outV, float* __restrict__ outF) {
  const int tid  = threadIdx.x;
  const int lane = tid & 63, wave = tid >> 6;
  const int l15 = lane & 15, lhi = lane >> 4;
  const int row0 = blockIdx.x * 128, col0 = blockIdx.y * 128;
  const int wrow = (wave >> 1) * 64, wcol = (wave & 1) * 64;

  __shared__ unsigned short As[128 * 32];
  __shared__ unsigned short Bs[128 * 32];

  f32x4 acc[4][4] = {};

  for (int kt = 0; kt < K; kt += 32) {
    #pragma unroll
    for (int c = 0; c < 2; ++c) {
      int base = wave * 1024 + c * 4096;            // byte base (wave-uniform)
      int o = base + lane * 16;                     // this lane's byte offset
      int r = o >> 6, cb = o & 63;                  // row, col-byte (64B rows)
      gload_lds16(A  + (size_t)(row0 + r) * K + kt + (cb >> 1), As + (base >> 1));
      gload_lds16(BT + (size_t)(col0 + r) * K + kt + (cb >> 1), Bs + (base >> 1));
    }
    __syncthreads();

    short8 af[4], bf[4];
    #pragma unroll
    for (int m = 0; m < 4; ++m)
      af[m] = *(const short8*)(As + (wrow + m * 16 + l15) * 32 + lhi * 8);
    #pragma unroll
    for (int n = 0; n < 4; ++n)
      bf[n] = *(const short8*)(Bs + (wcol + n * 16 + l15) * 32 + lhi * 8);
    #pragma unroll
    for (int m = 0; m < 4; ++m)
      #pragma unroll
      for (int n = 0; n < 4; ++n)
        acc[m][n] = mfma16x16x32(af[m], bf[n], acc[m][n]);
    __syncthreads();
  }

  #pragma unroll
  for (int m = 0; m < 4; ++m)
    #pragma unroll
    for (int n = 0; n < 4; ++n) {
      int col = col0 + wcol + n * 16 + l15;
      #pragma unroll
      for (int j = 0; j < 4; ++j) {
        int row = row0 + wrow + m * 16 + lhi * 4 + j;
        float v = acc[m][n][j];
        if (MODE == 0) {
          int proj = col >> 10, d = col & 1023;
          int h = d >> 6, hd = d & 63;
          int b = row >> 11, s = row & 2047;
          const float* bias = (proj == 0) ? bias0 : (proj == 1) ? bias1 : bias2;
          unsigned short* dst = (proj == 0) ? outQ : (proj == 1) ? outK : outV;
          dst[((size_t)((b * NUMH + h) * SEQ + s) << 6) + hd] = f2bf(v + bias[d]);
        } else {
          size_t idx = (size_t)row * N + col;
          outF[idx] = v + bias0[col] + resid[idx];
        }
      }
    }
}

// ---------------- V [BH][S][64] -> VT [BH][64][S] (bf16) ----------------
__global__ void k_vtrans(const unsigned short* __restrict__ V, unsigned short* __restrict__ VT) {
  __shared__ unsigned short t[64][65];
  int bh = blockIdx.y, s0 = blockIdx.x * 64;
  int tid = threadIdx.x;
  for (int it = 0; it < 16; ++it) {
    int idx = it * 256 + tid;
    int r = idx >> 6, c = idx & 63;
    t[r][c] = V[(size_t)(bh * SEQ + s0 + r) * 64 + c];
  }
  __syncthreads();
  for (int it = 0; it < 16; ++it) {
    int idx = it * 256 + tid;
    int d = idx >> 6, sl = idx & 63;
    VT[(size_t)(bh * 64 + d) * SEQ + s0 + sl] = t[sl][d];
  }
}

// ---------------- flash attention: swapped-QK^T 32x32 + 2-phase dbuf ----------
// grid (BH=32, SEQ/128=16): id = bh + 32*qtile -> id%8 = bh%8, so all q-tiles of
// one head land on the same XCD (K/V 512KB -> L2-resident). 256 thr, each wave
// owns 32 q-rows; KVBLK=64, double-buffered K/V staged via global_load_lds
// (issue-next BEFORE compute; __syncthreads' vmcnt-drain is then ~free).
__global__ __launch_bounds__(256, 2)
void k_attn(const unsigned short* __restrict__ Q, const unsigned short* __restrict__ Kk,
            const unsigned short* __restrict__ VT, const float* __restrict__ mask,
            unsigned short* __restrict__ ctx) {
  const int tid = threadIdx.x, lane = tid & 63, wave = tid >> 6;
  const int l31 = lane & 31, hi = lane >> 5;
  const int bh = blockIdx.x, b = bh >> 4, h = bh & 15;
  const int qs = blockIdx.y * 128 + wave * 32;    // this wave's 32 q-rows

  __shared__ __align__(16) unsigned short Ks[2][64 * 64];  // [64 key][64 d], XOR-swizzled
  __shared__ __align__(16) unsigned short Vs[2][64 * 64];  // [64 d][64 key], XOR-swizzled
  __shared__ __align__(16) float sLds[4][32];              // per-wave alpha / l broadcast

  // Q frag (B-operand): lane holds Q[qs+l31][ks*16 + hi*8 + i], i=0..7
  short8 qf[4];
  {
    const unsigned short* qrow = Q + ((size_t)bh * SEQ + qs + l31) * 64 + hi * 8;
    #pragma unroll
    for (int ks = 0; ks < 4; ++ks) qf[ks] = *(const short8*)(qrow + ks * 16);
  }

  f32x16 o0 = {}, o1 = {};          // O[q=crow(r,hi)][d = l31 | 32+l31]
  float mr = -3.0e38f, lr = 0.f;
  const float LOG2E = 1.44269504088896340736f;
  const float scale = 0.125f;       // 1/sqrt(64)
  const int sw = (l31 & 7) << 4;    // read-side XOR swizzle

  auto stage = [&](int bufi, int kt) {
    #pragma unroll
    for (int c = 0; c < 2; ++c) {
      int base = wave * 1024 + c * 4096;
      int off = base + lane * 16;
      int r = off >> 7, cb = off & 127;
      int scb = cb ^ ((r & 7) << 4);               // pre-swizzle the SOURCE
      gload_lds16(Kk + ((size_t)bh * SEQ + kt + r) * 64 + (scb >> 1), &Ks[bufi][base >> 1]);
      gload_lds16(VT + ((size_t)bh * 64 + r) * SEQ + kt + (scb >> 1), &Vs[bufi][base >> 1]);
    }
  };

  stage(0, 0);
  __syncthreads();
  int cur = 0;

  for (int kt = 0; kt < SEQ; kt += 64) {
    if (kt + 64 < SEQ) stage(cur ^ 1, kt + 64);    // issue next-tile loads EARLY

    // ---- S = K Q^T (swapped): s0 = keys kt+0..31, s1 = keys kt+32..63 ----
    const unsigned short* Kc = Ks[cur];
    const unsigned short* Vc = Vs[cur];
    f32x16 s0 = {}, s1 = {};
    #pragma unroll
    for (int ks = 0; ks < 4; ++ks) {
      int cb = ((ks * 16 + hi * 8) * 2) ^ sw;
      short8 k0 = *(const short8*)((const char*)Kc + l31 * 128 + cb);
      short8 k1 = *(const short8*)((const char*)Kc + (32 + l31) * 128 + cb);
      s0 = mfma32x32x16(k0, qf[ks], s0);
      s1 = mfma32x32x16(k1, qf[ks], s1);
    }

    // ---- mask (L2-hot): key(r) = 32*kb + 8*(r>>2) + 4*hi + (r&3) ----
    f32x4 mk0[4], mk1[4];
    #pragma unroll
    for (int rq = 0; rq < 4; ++rq) {
      mk0[rq] = *(const f32x4*)(mask + b * SEQ + kt + rq * 8 + hi * 4);
      mk1[rq] = *(const f32x4*)(mask + b * SEQ + kt + 32 + rq * 8 + hi * 4);
    }
    #pragma unroll
    for (int r = 0; r < 16; ++r) {
      s0[r] = fmaf(s0[r], scale, mk0[r >> 2][r & 3]);
      s1[r] = fmaf(s1[r], scale, mk1[r >> 2][r & 3]);
    }

    // ---- online softmax (per q = l31; partner lane hi^1 has other 32 keys) ----
    float tmax = fmaxf(s0[0], s1[0]);
    #pragma unroll
    for (int r = 1; r < 16; ++r) tmax = fmaxf(tmax, fmaxf(s0[r], s1[r]));
    tmax = xhalf_max(tmax);

    if (!__all(tmax <= mr + 8.0f)) {          // defer-max (T13, THR=8)
      float mnew = fmaxf(mr, tmax);
      float alpha = exp2f((mr - mnew) * LOG2E);
      mr = mnew; lr *= alpha;
      if (hi == 0) sLds[wave][l31] = alpha;   // redistribute alpha: col-index -> row-index
      f32x4 av[4];
      #pragma unroll
      for (int rq = 0; rq < 4; ++rq) av[rq] = *(const f32x4*)&sLds[wave][rq * 8 + hi * 4];
      #pragma unroll
      for (int r = 0; r < 16; ++r) {
        o0[r] *= av[r >> 2][r & 3];
        o1[r] *= av[r >> 2][r & 3];
      }
    }

    float mL = mr * LOG2E;
    float rs = 0.f;
    #pragma unroll
    for (int r = 0; r < 16; ++r) {
      float p0 = exp2f(fmaf(s0[r], LOG2E, -mL));
      float p1 = exp2f(fmaf(s1[r], LOG2E, -mL));
      s0[r] = p0; s1[r] = p1; rs += p0 + p1;
    }
    lr += xhalf_sum(rs);

    // ---- P -> bf16 A-frags via cvt_pk + permlane32_swap (T12) ----
    unsigned pw[4][4];
    #pragma unroll
    for (int ks = 0; ks < 4; ++ks) {
      int ro = 8 * (ks & 1);
      unsigned a0, a1, b0, b1;
      if (ks < 2) {
        a0 = cvtpk(s0[ro + 0], s0[ro + 1]); a1 = cvtpk(s0[ro + 2], s0[ro + 3]);
        b0 = cvtpk(s0[ro + 4], s0[ro + 5]); b1 = cvtpk(s0[ro + 6], s0[ro + 7]);
      } else {
        a0 = cvtpk(s1[ro + 0], s1[ro + 1]); a1 = cvtpk(s1[ro + 2], s1[ro + 3]);
        b0 = cvtpk(s1[ro + 4], s1[ro + 5]); b1 = cvtpk(s1[ro + 6], s1[ro + 7]);
      }
      perm32swap(a0, b0);
      perm32swap(a1, b1);
      pw[ks][0] = a0; pw[ks][1] = a1; pw[ks][2] = b0; pw[ks][3] = b1;
    }

    // ---- O += P V ----
    #pragma unroll
    for (int ks = 0; ks < 4; ++ks) {
      union { unsigned u[4]; short8 s; } pu;
      pu.u[0] = pw[ks][0]; pu.u[1] = pw[ks][1]; pu.u[2] = pw[ks][2]; pu.u[3] = pw[ks][3];
      int cb = ((ks * 16 + hi * 8) * 2) ^ sw;
      short8 v0 = *(const short8*)((const char*)Vc + l31 * 128 + cb);
      short8 v1 = *(const short8*)((const char*)Vc + (32 + l31) * 128 + cb);
      o0 = mfma32x32x16(pu.s, v0, o0);
      o1 = mfma32x32x16(pu.s, v1, o1);
    }

    __syncthreads();   // drains vmcnt (next-tile loads issued ~600cy ago) + protects buf reuse
    cur ^= 1;
  }

  // ---- epilogue: redistribute l (col-index -> row-index), normalize, store ----
  if (hi == 0) sLds[wave][l31] = lr;
  f32x4 lv[4];
  #pragma unroll
  for (int rq = 0; rq < 4; ++rq) {
    f32x4 t = *(const f32x4*)&sLds[wave][rq * 8 + hi * 4];
    lv[rq][0] = 1.f / t[0]; lv[rq][1] = 1.f / t[1];
    lv[rq][2] = 1.f / t[2]; lv[rq][3] = 1.f / t[3];
  }
  #pragma unroll
  for (int r = 0; r < 16; ++r) {
    int q = qs + (r & 3) + 8 * (r >> 2) + 4 * hi;
    float inv = lv[r >> 2][r & 3];
    unsigned short* dst = ctx + (size_t)(b * SEQ + q) * HID + h * 64;
    dst[l31]      = f2bf(o0[r] * inv);
    dst[32 + l31] = f2bf(o1[r] * inv);
  }
}

// ---------------- LayerNorm (input already has residual folded in) ----------------
__global__ __launch_bounds__(256)
void k_ln(const float* __restrict__ resid, const float* __restrict__ gamma,
          const float* __restrict__ beta, float* __restrict__ out) {
  int row = blockIdx.x, tid = threadIdx.x;
  f32x4 v = ((const f32x4*)(resid + (size_t)row * HID))[tid];
  float s = v[0] + v[1] + v[2] + v[3];
  float ss = v[0]*v[0] + v[1]*v[1] + v[2]*v[2] + v[3]*v[3];
  #pragma unroll
  for (int off = 1; off < 64; off <<= 1) { s += __shfl_xor(s, off); ss += __shfl_xor(ss, off); }
  __shared__ float sb[4], ssb[4];
  int wave = tid >> 6, lane = tid & 63;
  if (lane == 0) { sb[wave] = s; ssb[wave] = ss; }
  __syncthreads();
  float ts = sb[0] + sb[1] + sb[2] + sb[3];
  float tss = ssb[0] + ssb[1] + ssb[2] + ssb[3];
  float mu = ts * (1.f / HID);
  float var = tss * (1.f / HID) - mu * mu;
  float rstd = rsqrtf(var + LN_EPS);
  f32x4 g = ((const f32x4*)gamma)[tid];
  f32x4 be = ((const f32x4*)beta)[tid];
  f32x4 o;
  #pragma unroll
  for (int i = 0; i < 4; ++i) o[i] = (v[i] - mu) * rstd * g[i] + be[i];
  ((f32x4*)(out + (size_t)row * HID))[tid] = o;
}

extern "C" void kernel_launch(void* const* d_in, const int* in_sizes, int n_in,
                              void* d_out, int out_size, void* d_ws, size_t ws_size,
                              hipStream_t stream) {
  const float* x     = (const float*)d_in[0];
  const float* mask  = (const float*)d_in[1];
  const float* Wq    = (const float*)d_in[2];
  const float* bq    = (const float*)d_in[3];
  const float* Wk    = (const float*)d_in[4];
  const float* bk    = (const float*)d_in[5];
  const float* Wv    = (const float*)d_in[6];
  const float* bv    = (const float*)d_in[7];
  const float* Wo    = (const float*)d_in[8];
  const float* bo    = (const float*)d_in[9];
  const float* gamma = (const float*)d_in[10];
  const float* beta  = (const float*)d_in[11];
  float* out = (float*)d_out;

  char* w = (char*)d_ws;
  unsigned short* xb    = (unsigned short*)w; w += (size_t)NTOK * HID * 2;   // 8 MB
  unsigned short* WqkvT = (unsigned short*)w; w += (size_t)3 * HID * HID * 2;// 6 MB
  unsigned short* WoT   = (unsigned short*)w; w += (size_t)HID * HID * 2;    // 2 MB
  unsigned short* Qh    = (unsigned short*)w; w += (size_t)NTOK * HID * 2;   // 8 MB
  unsigned short* Kh    = (unsigned short*)w; w += (size_t)NTOK * HID * 2;   // 8 MB
  unsigned short* Vh    = (unsigned short*)w; w += (size_t)NTOK * HID * 2;   // 8 MB
  unsigned short* VTh   = (unsigned short*)w; w += (size_t)NTOK * HID * 2;   // 8 MB
  unsigned short* ctxb  = (unsigned short*)w; w += (size_t)NTOK * HID * 2;   // 8 MB
  float*          attn  = (float*)w;          w += (size_t)NTOK * HID * 4;   // 16 MB
  (void)ws_size; (void)in_sizes; (void)n_in; (void)out_size;

  k_conv_x<<<NTOK * HID / 4 / 256, 256, 0, stream>>>(x, xb);
  k_transw_all<<<dim3(32, 32, 4), dim3(32, 8), 0, stream>>>(Wq, Wk, Wv, Wo, WqkvT, WoT);

  k_gemm<0><<<dim3(NTOK / 128, 3 * HID / 128), 256, 0, stream>>>(
      xb, WqkvT, NTOK, 3 * HID, HID, bq, bk, bv, nullptr, Qh, Kh, Vh, nullptr);

  k_vtrans<<<dim3(SEQ / 64, BATCH * NUMH), 256, 0, stream>>>(Vh, VTh);

  k_attn<<<dim3(BATCH * NUMH, SEQ / 128), 256, 0, stream>>>(Qh, Kh, VTh, mask, ctxb);

  k_gemm<1><<<dim3(NTOK / 128, HID / 128), 256, 0, stream>>>(
      ctxb, WoT, NTOK, HID, HID, bo, nullptr, nullptr, x, nullptr, nullptr, nullptr, attn);

  k_ln<<<NTOK, 256, 0, stream>>>(attn, gamma, beta, out);
}